// Round 15
// baseline (397.558 us; speedup 1.0000x reference)
//
#include <hip/hip_runtime.h>
#include <stdint.h>
#include <math.h>

#define B_   4
#define T_   4096
#define BT_  16384
#define HID  2048
#define ED   256
#define HD   32
#define NH   8
#define K3   768    // packed split K (hi|hi|lo)
#define KW   6144   // packed split K for W2 = Wo@Wv (hi|hi|lo over 2048)
#define KSP  8      // K-split for W2 GEMM

typedef unsigned short u16;
typedef __attribute__((ext_vector_type(8))) short short8;
typedef __attribute__((ext_vector_type(4))) float f32x4;

typedef __attribute__((address_space(1))) void gvoid;
typedef __attribute__((address_space(3))) void lvoid;

__device__ __forceinline__ float bf2f(u16 h) {
    return __uint_as_float(((uint32_t)h) << 16);
}
__device__ __forceinline__ u16 f2bf(float f) {
    uint32_t u = __float_as_uint(f);
    u += 0x7FFFu + ((u >> 16) & 1u);   // round-to-nearest-even
    return (u16)(u >> 16);
}
__device__ __forceinline__ void gld_lds16(const void* g, void* l) {
    __builtin_amdgcn_global_load_lds((gvoid*)(uintptr_t)g, (lvoid*)(uintptr_t)l, 16, 0, 0);
}
__device__ __forceinline__ void BAR() {
    asm volatile("" ::: "memory");
    __builtin_amdgcn_s_barrier();
    asm volatile("" ::: "memory");
}

// ---- Wk -> packed [hi | lo | hi] rows of 768 (pairs with A3 = [hi | hi | lo]) ----
__global__ void k_cvt_wk3(const float* __restrict__ in, u16* __restrict__ out) {
    int i = blockIdx.x * 256 + threadIdx.x;   // over HID*ED
    int n = i >> 8, c = i & 255;
    float f = in[i];
    u16 h = f2bf(f);
    out[(size_t)n * K3 + c]       = h;
    out[(size_t)n * K3 + 256 + c] = f2bf(f - bf2f(h));
    out[(size_t)n * K3 + 512 + c] = h;
}

// ---- Wo (2048x2048 f32) -> WoP [2048][6144] = [hi | hi | lo] ----
__global__ void k_packWo(const float* __restrict__ wo, u16* __restrict__ wop) {
    int i = blockIdx.x * 256 + threadIdx.x;   // over 2048*2048
    int o = i >> 11, n = i & 2047;
    float f = wo[i];
    u16 h = f2bf(f);
    wop[(size_t)o * KW + n]        = h;
    wop[(size_t)o * KW + 2048 + n] = h;
    wop[(size_t)o * KW + 4096 + n] = f2bf(f - bf2f(h));
}

// ---- Wv (2048x256 f32, row n col c) -> WvP [256][6144] = [hi | lo | hi] (transposed) ----
__global__ void k_packWv(const float* __restrict__ wv, u16* __restrict__ wvp) {
    int i = blockIdx.x * 256 + threadIdx.x;   // over 2048*256
    int n = i >> 8, c = i & 255;
    float f = wv[i];
    u16 h = f2bf(f);
    wvp[(size_t)c * KW + n]        = h;
    wvp[(size_t)c * KW + 2048 + n] = f2bf(f - bf2f(h));
    wvp[(size_t)c * KW + 4096 + n] = h;
}

// ---- reduce 8 K-split partials -> W2 f32 -> W23 [2048][768] = [hi | lo | hi] ----
__global__ void k_w2pack(const float* __restrict__ part, u16* __restrict__ w23) {
    int i = blockIdx.x * 256 + threadIdx.x;   // over 2048*256
    int o = i >> 8, c = i & 255;
    float s = 0.f;
#pragma unroll
    for (int k = 0; k < KSP; ++k) s += part[(size_t)k * HID * ED + i];
    u16 h = f2bf(s);
    w23[(size_t)o * K3 + c]       = h;
    w23[(size_t)o * K3 + 256 + c] = f2bf(s - bf2f(h));
    w23[(size_t)o * K3 + 512 + c] = h;
}

// ---------------- hash-embedding gather (f32) ----------------
__global__ void k_gather(const int* __restrict__ hashes, const int* __restrict__ offs,
                         const float* __restrict__ tab, float* __restrict__ E) {
    const int bt = blockIdx.x;
    const int tid = threadIdx.x;          // 256 = 8 heads x 32 dims
    const int head = tid >> 5, d = tid & 31;
    const int row = hashes[bt * NH + head] + offs[head];
    E[(size_t)bt * ED + tid] = tab[(size_t)row * HD + d];
}

// ---- conv + LN + silu + residual; writes A3 row = [e_hi | e_hi | e_lo] (768) ----
__global__ void k_conv(const float* __restrict__ E, const float* __restrict__ w,
                       const float* __restrict__ lng, const float* __restrict__ lnb,
                       u16* __restrict__ a3) {
    const int bt = blockIdx.x;
    const int b = bt >> 12;               // T_ = 4096
    const int t = bt & 4095;
    const int ch = threadIdx.x;           // 256
    float c = 0.f;
#pragma unroll
    for (int k = 0; k < 4; ++k) {
        int tt = t - 9 + 3 * k;           // taps at t-9, t-6, t-3, t
        if (tt >= 0)
            c += w[ch * 4 + k] * E[((size_t)(b * T_ + tt)) * ED + ch];
    }
    float s = c, s2 = c * c;
#pragma unroll
    for (int o = 32; o; o >>= 1) { s += __shfl_xor(s, o); s2 += __shfl_xor(s2, o); }
    __shared__ float red[8];
    const int wid = ch >> 6, lane = ch & 63;
    if (!lane) { red[wid] = s; red[4 + wid] = s2; }
    __syncthreads();
    s  = red[0] + red[1] + red[2] + red[3];
    s2 = red[4] + red[5] + red[6] + red[7];
    const float mean = s * (1.f / 256.f);
    const float var  = s2 * (1.f / 256.f) - mean * mean;
    float ln = (c - mean) * rsqrtf(var + 1e-5f) * lng[ch] + lnb[ch];
    float si = ln / (1.f + expf(-ln));    // silu
    float ev = E[(size_t)bt * ED + ch] + si;
    u16 h = f2bf(ev);
    a3[(size_t)bt * K3 + ch]       = h;
    a3[(size_t)bt * K3 + 256 + ch] = h;
    a3[(size_t)bt * K3 + 512 + ch] = f2bf(ev - bf2f(h));
}

// ---------------- per-row x stats: mu, rsqrt(var+eps) ----------------
__global__ void k_xstat(const float* __restrict__ x, float* __restrict__ xs) {
    const int m = blockIdx.x;
    const int tid = threadIdx.x;          // 256 thr, 2 float4 each
    const f32x4* xr = (const f32x4*)(x + (size_t)m * HID);
    float sx = 0.f, sx2 = 0.f;
#pragma unroll
    for (int i = 0; i < 2; ++i) {
        f32x4 xv = xr[tid + i * 256];
#pragma unroll
        for (int c = 0; c < 4; ++c) { sx += xv[c]; sx2 += xv[c] * xv[c]; }
    }
#pragma unroll
    for (int o = 32; o; o >>= 1) { sx += __shfl_xor(sx, o); sx2 += __shfl_xor(sx2, o); }
    __shared__ float red[8];
    const int wid = tid >> 6, lane = tid & 63;
    if (!lane) { red[wid] = sx; red[4 + wid] = sx2; }
    __syncthreads();
    if (tid == 0) {
        sx  = red[0] + red[1] + red[2] + red[3];
        sx2 = red[4] + red[5] + red[6] + red[7];
        const float inv = 1.f / (float)HID;
        const float mu = sx * inv, var = sx2 * inv - mu * mu;
        xs[m * 2]     = mu;
        xs[m * 2 + 1] = rsqrtf(var + 1e-5f);
    }
}

// ---------------- finalize gamma from 8x4 partial slices ----------------
// dot = rk*(T1 - mu_k*T2) + T3 ; partial[m][nb][wc][5] = {S1,S2,T1,T2,T3}
__global__ void k_gamma2(const float* __restrict__ partial, float* __restrict__ gamma) {
    const int m = blockIdx.x * 256 + threadIdx.x;
    float s[5] = {0.f, 0.f, 0.f, 0.f, 0.f};
    const float* p = partial + (size_t)m * 160;
#pragma unroll
    for (int nb = 0; nb < 32; ++nb)
#pragma unroll
        for (int v = 0; v < 5; ++v) s[v] += p[nb * 5 + v];
    const float inv = 1.f / (float)HID;
    const float mu = s[0] * inv, var = s[1] * inv - mu * mu;
    const float rk = rsqrtf(var + 1e-5f);
    const float dot = rk * (s[2] - mu * s[3]) + s[4];
    const float gd = dot * 0.022097086912079608f;   // 1/sqrt(2048)
    const float sg = (gd > 0.f) ? 1.f : ((gd < 0.f) ? -1.f : 0.f);
    const float sv = sqrtf(fmaxf(fabsf(gd), 1e-6f)) * sg;
    gamma[m] = 1.f / (1.f + expf(-sv));
}

// ================= 256x256 / BK=64 bf16 MFMA GEMM — persistent 2-tile =================
// (r10/r11-validated core: chunk-pure reads, 4-phase staging, vmcnt(6).)
// A row = mh*128 + wr*64 + fm*16 + l15 (P1 reads exactly A h0, P3 exactly h1)
// B row = nh*128 + wc*32 + fn*16 + l15 (P1 reads exactly B h0, P2 exactly h1)
// Schedule (tile t, buf p=t&1): P1 reads Ah0,Bh0 + stage Ah1(t+1)->p^1; P2 reads
// Bh1 + stage Ah0(t+2)->p; P3 reads Ah1 + stage Bh0(t+2)->p; P4 regs-only +
// stage Bh1(t+2)->p + vmcnt(6) (drains ALL of t+1, issued 4-8 phases earlier).
// r15 PERSISTENT 2-TILE (NT=2, grid 256 = 1 block/CU, single round): each block
// keeps its m-panel and runs two n-tiles (nblk, nblk+1024). After tile-0's
// K-loop (final BAR -> LDS fully free), it issues tile-1's ENTIRE 16-load
// prologue and THEN runs tile-0's epilogue — staging flies under the epilogue
// stores; tile-1 starts at vmcnt(8)+BAR exactly like a fresh prologue. Halves
// block count (one fill/drain round instead of two) and halves A-panel fetch.
// EPI2's epilogue writes per-wc partials DIRECTLY to global (no LDS red buffer
// — it would collide with the prefetched tile-1 data; r14 showed LDS-reduction
// cost anyway). EPI: 0 = f32 K-split slab; 2 = fused key->gamma partials;
// 3 = f32 store with rowscale.
template <int EPI, int GRID, int NT>
__global__ __launch_bounds__(512, 2)
void gemm8(const u16* __restrict__ A, int lda, const u16* __restrict__ Bm, int ldb,
           const float* __restrict__ rowscale, void* __restrict__ Cout,
           int M, int N, int K,
           const float* __restrict__ xq, const float* __restrict__ xs,
           const float* __restrict__ gq, const float* __restrict__ bq,
           const float* __restrict__ gk, const float* __restrict__ bk,
           float* __restrict__ partial) {
    extern __shared__ char smem[];
    const int tid = threadIdx.x, wid = tid >> 6, lane = tid & 63;
    const int l15 = lane & 15, lhi = lane >> 4;
    const int wr = wid >> 2, wc = wid & 3;

    const int id = blockIdx.x;
    int mblk, nblk0;
    if (GRID == 0) {
        // 256 blocks: xcd = id&7 owns an 8(m) x 4(n-pairs) chunk; NT=2 covers n+4
        const int xcd = id & 7, loc = id >> 3;
        mblk  = ((xcd << 3) + (loc & 7)) << 8;
        nblk0 = (loc >> 3) << 8;
    } else {
        const int tiles_m = M >> 8;
        mblk  = (id % tiles_m) << 8;
        nblk0 = (id / tiles_m) << 8;
        const size_t koff = (size_t)blockIdx.y * K;
        A  += koff;
        Bm += koff;
    }

    const int srow = tid >> 3;
    const int scol = ((tid & 7) << 3) ^ ((srow & 7) << 3);
    const u16* aS[4];
    const u16* bS[4];
#pragma unroll
    for (int h = 0; h < 2; ++h)
#pragma unroll
        for (int r = 0; r < 2; ++r) {
            aS[h * 2 + r] = A  + (size_t)(mblk + h * 128 + r * 64 + srow) * lda + scol;
            bS[h * 2 + r] = Bm + (size_t)(nblk0 + h * 128 + r * 64 + srow) * ldb + scol;
        }
    const int wb = wid * 1024;

    const int koff0 = (lhi * 16) ^ ((l15 & 7) << 4);
    const int koff1 = (64 + lhi * 16) ^ ((l15 & 7) << 4);

    short8 ar[4][2], br[2][2][2];
    f32x4 acc[8][4];

#define SA(h, tt) do { const int kk_ = (tt) << 6;                                    \
        char* d_ = smem + (((tt) & 1) * 32768) + (h) * 16384 + wb;                   \
        gld_lds16(aS[(h) * 2 + 0] + kk_, d_);                                        \
        gld_lds16(aS[(h) * 2 + 1] + kk_, d_ + 8192); } while (0)
#define SB(h, tt) do { const int kk_ = (tt) << 6;                                    \
        char* d_ = smem + 65536 + (((tt) & 1) * 32768) + (h) * 16384 + wb;           \
        gld_lds16(bS[(h) * 2 + 0] + kk_, d_);                                        \
        gld_lds16(bS[(h) * 2 + 1] + kk_, d_ + 8192); } while (0)
#define LDA_SUB(mh, p) do {                                                          \
        const char* ab_ = smem + (p) * 32768 + ((mh) * 128 + wr * 64) * 128;         \
        _Pragma("unroll") for (int fm = 0; fm < 4; ++fm) {                           \
            const char* rb_ = ab_ + (fm * 16 + l15) * 128;                           \
            ar[fm][0] = *(const short8*)(rb_ + koff0);                               \
            ar[fm][1] = *(const short8*)(rb_ + koff1); } } while (0)
#define LDB_SUB(nh, p) do {                                                          \
        const char* bb_ = smem + 65536 + (p) * 32768 + ((nh) * 128 + wc * 32) * 128; \
        _Pragma("unroll") for (int fn = 0; fn < 2; ++fn) {                           \
            const char* rb_ = bb_ + (fn * 16 + l15) * 128;                           \
            br[nh][fn][0] = *(const short8*)(rb_ + koff0);                           \
            br[nh][fn][1] = *(const short8*)(rb_ + koff1); } } while (0)
#define MMQ(mh, nh) do { __builtin_amdgcn_s_setprio(1);                              \
        _Pragma("unroll") for (int fm = 0; fm < 4; ++fm)                             \
        _Pragma("unroll") for (int fn = 0; fn < 2; ++fn) {                           \
            acc[(mh) * 4 + fm][(nh) * 2 + fn] = __builtin_amdgcn_mfma_f32_16x16x32_bf16( \
                ar[fm][0], br[nh][fn][0], acc[(mh) * 4 + fm][(nh) * 2 + fn], 0, 0, 0);   \
            acc[(mh) * 4 + fm][(nh) * 2 + fn] = __builtin_amdgcn_mfma_f32_16x16x32_bf16( \
                ar[fm][1], br[nh][fn][1], acc[(mh) * 4 + fm][(nh) * 2 + fn], 0, 0, 0); } \
        __builtin_amdgcn_s_setprio(0); } while (0)

    // prologue for tile 0: tiles 0,1 fully staged (16 loads)
    SA(0, 0); SA(1, 0); SB(0, 0); SB(1, 0);
    SA(0, 1); SA(1, 1); SB(0, 1); SB(1, 1);

    const int nk = K >> 6;
#pragma unroll
    for (int tile = 0; tile < NT; ++tile) {
        const int nblk = nblk0 + tile * 1024;

#pragma unroll
        for (int i = 0; i < 8; ++i)
#pragma unroll
            for (int j = 0; j < 4; ++j) acc[i][j] = f32x4{0.f, 0.f, 0.f, 0.f};

        // 16 loads in flight (issued by prologue or previous tile's tail)
        asm volatile("s_waitcnt vmcnt(8)" ::: "memory");
        BAR();

        for (int t = 0; t < nk; ++t) {
            const int p = t & 1;
            // P1: reads Ah0,Bh0 of buf p; stage Ah1(t+1) -> p^1 (freed (t-1).P3)
            LDA_SUB(0, p); LDB_SUB(0, p);
            if (t >= 1 && t + 1 < nk) SA(1, t + 1);
            BAR(); MMQ(0, 0); BAR();
            // P2: reads Bh1; stage Ah0(t+2) -> p (region freed at P1)
            LDB_SUB(1, p);
            if (t + 2 < nk) SA(0, t + 2);
            BAR(); MMQ(0, 1); BAR();
            // P3: reads Ah1; stage Bh0(t+2) -> p (freed at P1)
            LDA_SUB(1, p);
            if (t + 2 < nk) SB(0, t + 2);
            BAR(); MMQ(1, 0); BAR();
            // P4: regs only; stage Bh1(t+2) -> p (freed at P2); vmcnt(6)
            if (t + 2 < nk) {
                SB(1, t + 2);
                asm volatile("s_waitcnt vmcnt(6)" ::: "memory");
            } else {
                asm volatile("s_waitcnt vmcnt(0)" ::: "memory");
            }
            BAR(); MMQ(1, 1); BAR();
        }
        // LDS fully free here (every ds_read completed before its MFMA issued,
        // and the final BAR synchronized all waves).

        if (tile + 1 < NT) {
            // retarget B pointers to the next n-tile and prefetch its entire
            // prologue (16 loads) BEFORE this tile's epilogue: staging overlaps
            // the epilogue's global stores. A pointers unchanged (same mblk).
#pragma unroll
            for (int h = 0; h < 2; ++h)
#pragma unroll
                for (int r = 0; r < 2; ++r)
                    bS[h * 2 + r] += (size_t)1024 * ldb;
            SA(0, 0); SA(1, 0); SB(0, 0); SB(1, 0);
            SA(0, 1); SA(1, 1); SB(0, 1); SB(1, 1);
        }

        // ---------------- epilogue for this tile ----------------
        if (EPI == 2) {
            // fused key->gamma partials, straight to global (no LDS)
            float gqv[4], bqv[4], gkv[4], bkv[4];
#pragma unroll
            for (int nj = 0; nj < 4; ++nj) {
                const int n = nblk + (nj >> 1) * 128 + wc * 32 + (nj & 1) * 16 + l15;
                gqv[nj] = gq[n]; bqv[nj] = bq[n]; gkv[nj] = gk[n]; bkv[nj] = bk[n];
            }
            const int nb = nblk >> 8;
#pragma unroll
            for (int mi = 0; mi < 8; ++mi) {
#pragma unroll
                for (int rr = 0; rr < 4; ++rr) {
                    const int rloc = (mi >> 2) * 128 + wr * 64 + (mi & 3) * 16 + lhi * 4 + rr;
                    const int m = mblk + rloc;
                    const float mu = xs[m * 2], rx = xs[m * 2 + 1];
                    float s1 = 0.f, s2 = 0.f, t1 = 0.f, t2 = 0.f, t3 = 0.f;
#pragma unroll
                    for (int nj = 0; nj < 4; ++nj) {
                        const float kv = acc[mi][nj][rr];
                        const int n = nblk + (nj >> 1) * 128 + wc * 32 + (nj & 1) * 16 + l15;
                        const float xv = xq[(size_t)m * N + n];
                        const float q  = (xv - mu) * rx * gqv[nj] + bqv[nj];
                        const float qg = q * gkv[nj];
                        s1 += kv; s2 += kv * kv;
                        t1 += qg * kv; t2 += qg; t3 += q * bkv[nj];
                    }
#pragma unroll
                    for (int o = 1; o < 16; o <<= 1) {
                        s1 += __shfl_xor(s1, o); s2 += __shfl_xor(s2, o);
                        t1 += __shfl_xor(t1, o); t2 += __shfl_xor(t2, o);
                        t3 += __shfl_xor(t3, o);
                    }
                    if (l15 == 0) {
                        float* d = partial + (((size_t)m * 8 + nb) * 4 + wc) * 5;
                        d[0] = s1; d[1] = s2; d[2] = t1; d[3] = t2; d[4] = t3;
                    }
                }
            }
        } else {
            float* Cf = (float*)Cout;
            if (EPI == 0 && GRID == 1) Cf += (size_t)blockIdx.y * M * N;   // K-split slab
#pragma unroll
            for (int mi = 0; mi < 8; ++mi) {
#pragma unroll
                for (int rr = 0; rr < 4; ++rr) {
                    const int m = mblk + (mi >> 2) * 128 + wr * 64 + (mi & 3) * 16 + lhi * 4 + rr;
                    const float sc = (EPI == 3) ? rowscale[m] : 1.0f;
#pragma unroll
                    for (int nj = 0; nj < 4; ++nj) {
                        const int n = nblk + (nj >> 1) * 128 + wc * 32 + (nj & 1) * 16 + l15;
                        Cf[(size_t)m * N + n] = acc[mi][nj][rr] * sc;
                    }
                }
            }
        }
    }
#undef SA
#undef SB
#undef LDA_SUB
#undef LDB_SUB
#undef MMQ
}

extern "C" void kernel_launch(void* const* d_in, const int* in_sizes, int n_in,
                              void* d_out, int out_size, void* d_ws, size_t ws_size,
                              hipStream_t stream) {
    const float* x      = (const float*)d_in[0];
    const int*   hashes = (const int*)d_in[1];
    const int*   offs   = (const int*)d_in[2];
    const float* emb    = (const float*)d_in[3];
    const float* conv_w = (const float*)d_in[4];
    const float* lncg   = (const float*)d_in[5];
    const float* lncb   = (const float*)d_in[6];
    const float* Wk     = (const float*)d_in[7];
    const float* Wv     = (const float*)d_in[8];
    const float* Wo     = (const float*)d_in[9];
    const float* lnkg   = (const float*)d_in[10];
    const float* lnkb   = (const float*)d_in[11];
    const float* lnqg   = (const float*)d_in[12];
    const float* lnqb   = (const float*)d_in[13];

    // ws (~95 MB). E (16.8MB, dead after k_conv) aliases W2part. key/value never
    // materialized: out = gamma * (e @ (Wo@Wv)^T).
    char* p = (char*)d_ws;
    float* E      = (float*)p;
    float* W2part = (float*)p;  p += (size_t)KSP * HID * ED * 4;  // 16.8 MB
    u16*   A3     = (u16*)p;    p += (size_t)BT_ * K3 * 2;        // 25.2 MB
    u16*   Wk3    = (u16*)p;    p += (size_t)HID * K3 * 2;        // 3.1 MB
    u16*   WoP    = (u16*)p;    p += (size_t)HID * KW * 2;        // 25.2 MB
    u16*   WvP    = (u16*)p;    p += (size_t)ED * KW * 2;         // 3.1 MB
    u16*   W23    = (u16*)p;    p += (size_t)HID * K3 * 2;        // 3.1 MB
    float* xs     = (float*)p;  p += (size_t)BT_ * 2 * 4;         // 128 KB
    float* part   = (float*)p;  p += (size_t)BT_ * 8 * 4 * 5 * 4; // 10.5 MB
    float* gamma  = (float*)p;  p += (size_t)BT_ * 4;             // 64 KB

    hipFuncSetAttribute((const void*)gemm8<0, 1, 1>,
                        hipFuncAttributeMaxDynamicSharedMemorySize, 131072);
    hipFuncSetAttribute((const void*)gemm8<2, 0, 2>,
                        hipFuncAttributeMaxDynamicSharedMemorySize, 131072);
    hipFuncSetAttribute((const void*)gemm8<3, 0, 2>,
                        hipFuncAttributeMaxDynamicSharedMemorySize, 131072);

    k_cvt_wk3<<<(HID * ED) / 256, 256, 0, stream>>>(Wk, Wk3);
    k_packWo<<<(HID * HID) / 256, 256, 0, stream>>>(Wo, WoP);
    k_packWv<<<(HID * ED) / 256, 256, 0, stream>>>(Wv, WvP);
    k_gather<<<BT_, 256, 0, stream>>>(hashes, offs, emb, E);
    k_conv<<<BT_, 256, 0, stream>>>(E, conv_w, lncg, lncb, A3);
    k_xstat<<<BT_, 256, 0, stream>>>(x, xs);

    // W2 = Wo @ Wv split-precision, K-split 8 x 768 -> f32 slabs (over dead E)
    gemm8<0, 1, 1><<<dim3(HID / 256, KSP), 512, 131072, stream>>>(
        WoP, KW, WvP, KW, nullptr, W2part, HID, ED, KW / KSP,
        nullptr, nullptr, nullptr, nullptr, nullptr, nullptr, nullptr);
    k_w2pack<<<(HID * ED) / 256, 256, 0, stream>>>(W2part, W23);

    const dim3 grid((BT_ / 256) * (HID / 256) / 2);   // 256 persistent 2-tile blocks
    // key partials: A3 @ Wk3^T (K=768), gamma reduction fused in epilogue
    gemm8<2, 0, 2><<<grid, 512, 131072, stream>>>(
        A3, K3, Wk3, K3, nullptr, nullptr, BT_, HID, K3,
        x, xs, lnqg, lnqb, lnkg, lnkb, part);
    k_gamma2<<<BT_ / 256, 256, 0, stream>>>(part, gamma);
    // out = gamma * (A3 @ W23^T)  (K=768) -> d_out f32
    gemm8<3, 0, 2><<<grid, 512, 131072, stream>>>(
        A3, K3, W23, K3, gamma, d_out, BT_, HID, K3,
        nullptr, nullptr, nullptr, nullptr, nullptr, nullptr, nullptr);
}

// Round 16
// 289.604 us; speedup vs baseline: 1.3728x; 1.3728x over previous
//
#include <hip/hip_runtime.h>
#include <stdint.h>
#include <math.h>

#define B_   4
#define T_   4096
#define BT_  16384
#define HID  2048
#define ED   256
#define HD   32
#define NH   8
#define K3   768    // packed split K (hi|hi|lo)
#define KW   6144   // packed split K for W2 = Wo@Wv (hi|hi|lo over 2048)
#define KSP  8      // K-split for W2 GEMM

typedef unsigned short u16;
typedef __attribute__((ext_vector_type(8))) short short8;
typedef __attribute__((ext_vector_type(4))) float f32x4;

typedef __attribute__((address_space(1))) void gvoid;
typedef __attribute__((address_space(3))) void lvoid;

__device__ __forceinline__ float bf2f(u16 h) {
    return __uint_as_float(((uint32_t)h) << 16);
}
__device__ __forceinline__ u16 f2bf(float f) {
    uint32_t u = __float_as_uint(f);
    u += 0x7FFFu + ((u >> 16) & 1u);   // round-to-nearest-even
    return (u16)(u >> 16);
}
__device__ __forceinline__ void gld_lds16(const void* g, void* l) {
    __builtin_amdgcn_global_load_lds((gvoid*)(uintptr_t)g, (lvoid*)(uintptr_t)l, 16, 0, 0);
}
__device__ __forceinline__ void BAR() {
    asm volatile("" ::: "memory");
    __builtin_amdgcn_s_barrier();
    asm volatile("" ::: "memory");
}

// ---- Wk -> packed [hi | lo | hi] rows of 768 (pairs with A3 = [hi | hi | lo]) ----
__global__ void k_cvt_wk3(const float* __restrict__ in, u16* __restrict__ out) {
    int i = blockIdx.x * 256 + threadIdx.x;   // over HID*ED
    int n = i >> 8, c = i & 255;
    float f = in[i];
    u16 h = f2bf(f);
    out[(size_t)n * K3 + c]       = h;
    out[(size_t)n * K3 + 256 + c] = f2bf(f - bf2f(h));
    out[(size_t)n * K3 + 512 + c] = h;
}

// ---- Wo (2048x2048 f32) -> WoP [2048][6144] = [hi | hi | lo] ----
__global__ void k_packWo(const float* __restrict__ wo, u16* __restrict__ wop) {
    int i = blockIdx.x * 256 + threadIdx.x;   // over 2048*2048
    int o = i >> 11, n = i & 2047;
    float f = wo[i];
    u16 h = f2bf(f);
    wop[(size_t)o * KW + n]        = h;
    wop[(size_t)o * KW + 2048 + n] = h;
    wop[(size_t)o * KW + 4096 + n] = f2bf(f - bf2f(h));
}

// ---- Wv (2048x256 f32, row n col c) -> WvP [256][6144] = [hi | lo | hi] (transposed) ----
__global__ void k_packWv(const float* __restrict__ wv, u16* __restrict__ wvp) {
    int i = blockIdx.x * 256 + threadIdx.x;   // over 2048*256
    int n = i >> 8, c = i & 255;
    float f = wv[i];
    u16 h = f2bf(f);
    wvp[(size_t)c * KW + n]        = h;
    wvp[(size_t)c * KW + 2048 + n] = f2bf(f - bf2f(h));
    wvp[(size_t)c * KW + 4096 + n] = h;
}

// ---- reduce 8 K-split partials -> W2 f32 -> W23 [2048][768] = [hi | lo | hi] ----
__global__ void k_w2pack(const float* __restrict__ part, u16* __restrict__ w23) {
    int i = blockIdx.x * 256 + threadIdx.x;   // over 2048*256
    int o = i >> 8, c = i & 255;
    float s = 0.f;
#pragma unroll
    for (int k = 0; k < KSP; ++k) s += part[(size_t)k * HID * ED + i];
    u16 h = f2bf(s);
    w23[(size_t)o * K3 + c]       = h;
    w23[(size_t)o * K3 + 256 + c] = f2bf(s - bf2f(h));
    w23[(size_t)o * K3 + 512 + c] = h;
}

// ---- FUSED gather + conv + LN + silu + residual; A3 row = [e_hi | e_hi | e_lo] ----
// r16: k_gather eliminated — taps gathered directly from the embedding table
// (tap rows are L2-shared across neighboring t); saves the E round-trip.
__global__ void k_conv(const int* __restrict__ hashes, const int* __restrict__ offs,
                       const float* __restrict__ tab, const float* __restrict__ w,
                       const float* __restrict__ lng, const float* __restrict__ lnb,
                       u16* __restrict__ a3) {
    const int bt = blockIdx.x;
    const int b = bt >> 12;               // T_ = 4096
    const int t = bt & 4095;
    const int ch = threadIdx.x;           // 256
    const int head = ch >> 5, d = ch & 31;
    const int off = offs[head];
    float c = 0.f, self = 0.f;
#pragma unroll
    for (int k = 0; k < 4; ++k) {
        const int tt = t - 9 + 3 * k;     // taps at t-9, t-6, t-3, t
        if (tt >= 0) {
            const int row = hashes[(b * T_ + tt) * NH + head] + off;
            const float ev = tab[(size_t)row * HD + d];
            c += w[ch * 4 + k] * ev;
            if (k == 3) self = ev;        // k=3 -> tt == t (always >= 0)
        }
    }
    float s = c, s2 = c * c;
#pragma unroll
    for (int o = 32; o; o >>= 1) { s += __shfl_xor(s, o); s2 += __shfl_xor(s2, o); }
    __shared__ float red[8];
    const int wid = ch >> 6, lane = ch & 63;
    if (!lane) { red[wid] = s; red[4 + wid] = s2; }
    __syncthreads();
    s  = red[0] + red[1] + red[2] + red[3];
    s2 = red[4] + red[5] + red[6] + red[7];
    const float mean = s * (1.f / 256.f);
    const float var  = s2 * (1.f / 256.f) - mean * mean;
    float ln = (c - mean) * rsqrtf(var + 1e-5f) * lng[ch] + lnb[ch];
    float si = ln / (1.f + expf(-ln));    // silu
    float ev = self + si;
    u16 h = f2bf(ev);
    a3[(size_t)bt * K3 + ch]       = h;
    a3[(size_t)bt * K3 + 256 + ch] = h;
    a3[(size_t)bt * K3 + 512 + ch] = f2bf(ev - bf2f(h));
}

// ---------------- per-row x stats: mu, rsqrt(var+eps) ----------------
__global__ void k_xstat(const float* __restrict__ x, float* __restrict__ xs) {
    const int m = blockIdx.x;
    const int tid = threadIdx.x;          // 256 thr, 2 float4 each
    const f32x4* xr = (const f32x4*)(x + (size_t)m * HID);
    float sx = 0.f, sx2 = 0.f;
#pragma unroll
    for (int i = 0; i < 2; ++i) {
        f32x4 xv = xr[tid + i * 256];
#pragma unroll
        for (int c = 0; c < 4; ++c) { sx += xv[c]; sx2 += xv[c] * xv[c]; }
    }
#pragma unroll
    for (int o = 32; o; o >>= 1) { sx += __shfl_xor(sx, o); sx2 += __shfl_xor(sx2, o); }
    __shared__ float red[8];
    const int wid = tid >> 6, lane = tid & 63;
    if (!lane) { red[wid] = sx; red[4 + wid] = sx2; }
    __syncthreads();
    if (tid == 0) {
        sx  = red[0] + red[1] + red[2] + red[3];
        sx2 = red[4] + red[5] + red[6] + red[7];
        const float inv = 1.f / (float)HID;
        const float mu = sx * inv, var = sx2 * inv - mu * mu;
        xs[m * 2]     = mu;
        xs[m * 2 + 1] = rsqrtf(var + 1e-5f);
    }
}

// ---------------- finalize gamma from 8 partial slices ----------------
// dot = rk*(T1 - mu_k*T2) + T3 ; partial[m][nb][5] = {S1,S2,T1,T2,T3}
__global__ void k_gamma2(const float* __restrict__ partial, float* __restrict__ gamma) {
    const int m = blockIdx.x * 256 + threadIdx.x;
    float s[5] = {0.f, 0.f, 0.f, 0.f, 0.f};
    const float* p = partial + (size_t)m * 40;
#pragma unroll
    for (int nb = 0; nb < 8; ++nb)
#pragma unroll
        for (int v = 0; v < 5; ++v) s[v] += p[nb * 5 + v];
    const float inv = 1.f / (float)HID;
    const float mu = s[0] * inv, var = s[1] * inv - mu * mu;
    const float rk = rsqrtf(var + 1e-5f);
    const float dot = rk * (s[2] - mu * s[3]) + s[4];
    const float gd = dot * 0.022097086912079608f;   // 1/sqrt(2048)
    const float sg = (gd > 0.f) ? 1.f : ((gd < 0.f) ? -1.f : 0.f);
    const float sv = sqrtf(fmaxf(fabsf(gd), 1e-6f)) * sg;
    gamma[m] = 1.f / (1.f + expf(-sv));
}

// ================= 256x256 / BK=64 bf16 MFMA GEMM — pipelined, chunk-aligned =================
// (r10/r11-validated core: chunk-pure reads, 4-phase staging, vmcnt(6).)
// A row = mh*128 + wr*64 + fm*16 + l15 (P1 reads exactly A h0, P3 exactly h1)
// B row = nh*128 + wc*32 + fn*16 + l15 (P1 reads exactly B h0, P2 exactly h1)
// Schedule (tile t, buf p=t&1): P1 reads Ah0,Bh0 + stage Ah1(t+1)->p^1; P2 reads
// Bh1 + stage Ah0(t+2)->p; P3 reads Ah1 + stage Bh0(t+2)->p; P4 regs-only +
// stage Bh1(t+2)->p + vmcnt(6) (drains ALL of t+1, issued 4-8 phases earlier).
// GRID=0: 2D XCD chunking (grid 64x8 tiles). GRID=1: row-major + K-split via
// blockIdx.y. EPI: 0 = f32 K-split slab; 2 = fused key->gamma partials
// (key never materialized); 3 = f32 store with rowscale.
template <int EPI, int GRID>
__global__ __launch_bounds__(512, 2)
void gemm8(const u16* __restrict__ A, int lda, const u16* __restrict__ Bm, int ldb,
           const float* __restrict__ rowscale, void* __restrict__ Cout,
           int M, int N, int K,
           const float* __restrict__ xq, const float* __restrict__ xs,
           const float* __restrict__ gq, const float* __restrict__ bq,
           const float* __restrict__ gk, const float* __restrict__ bk,
           float* __restrict__ partial) {
    extern __shared__ char smem[];
    const int tid = threadIdx.x, wid = tid >> 6, lane = tid & 63;
    const int l15 = lane & 15, lhi = lane >> 4;
    const int wr = wid >> 2, wc = wid & 3;

    const int id = blockIdx.x;
    int mblk, nblk;
    if (GRID == 0) {
        // 2D XCD chunking: xcd = id&7 owns an 8(m) x 8(n) tile chunk
        const int xcd = id & 7, loc = id >> 3;
        mblk = ((xcd << 3) + (loc & 7)) << 8;
        nblk = (loc >> 3) << 8;
    } else {
        const int tiles_m = M >> 8;
        mblk = (id % tiles_m) << 8;
        nblk = (id / tiles_m) << 8;
        const size_t koff = (size_t)blockIdx.y * K;
        A  += koff;
        Bm += koff;
    }

    f32x4 acc[8][4];
#pragma unroll
    for (int i = 0; i < 8; ++i)
#pragma unroll
        for (int j = 0; j < 4; ++j) acc[i][j] = f32x4{0.f, 0.f, 0.f, 0.f};

    const int srow = tid >> 3;
    const int scol = ((tid & 7) << 3) ^ ((srow & 7) << 3);
    const u16* aS[4];
    const u16* bS[4];
#pragma unroll
    for (int h = 0; h < 2; ++h)
#pragma unroll
        for (int r = 0; r < 2; ++r) {
            aS[h * 2 + r] = A  + (size_t)(mblk + h * 128 + r * 64 + srow) * lda + scol;
            bS[h * 2 + r] = Bm + (size_t)(nblk + h * 128 + r * 64 + srow) * ldb + scol;
        }
    const int wb = wid * 1024;

    const int koff0 = (lhi * 16) ^ ((l15 & 7) << 4);
    const int koff1 = (64 + lhi * 16) ^ ((l15 & 7) << 4);

    short8 ar[4][2], br[2][2][2];

#define SA(h, tt) do { const int kk_ = (tt) << 6;                                    \
        char* d_ = smem + (((tt) & 1) * 32768) + (h) * 16384 + wb;                   \
        gld_lds16(aS[(h) * 2 + 0] + kk_, d_);                                        \
        gld_lds16(aS[(h) * 2 + 1] + kk_, d_ + 8192); } while (0)
#define SB(h, tt) do { const int kk_ = (tt) << 6;                                    \
        char* d_ = smem + 65536 + (((tt) & 1) * 32768) + (h) * 16384 + wb;           \
        gld_lds16(bS[(h) * 2 + 0] + kk_, d_);                                        \
        gld_lds16(bS[(h) * 2 + 1] + kk_, d_ + 8192); } while (0)
#define LDA_SUB(mh, p) do {                                                          \
        const char* ab_ = smem + (p) * 32768 + ((mh) * 128 + wr * 64) * 128;         \
        _Pragma("unroll") for (int fm = 0; fm < 4; ++fm) {                           \
            const char* rb_ = ab_ + (fm * 16 + l15) * 128;                           \
            ar[fm][0] = *(const short8*)(rb_ + koff0);                               \
            ar[fm][1] = *(const short8*)(rb_ + koff1); } } while (0)
#define LDB_SUB(nh, p) do {                                                          \
        const char* bb_ = smem + 65536 + (p) * 32768 + ((nh) * 128 + wc * 32) * 128; \
        _Pragma("unroll") for (int fn = 0; fn < 2; ++fn) {                           \
            const char* rb_ = bb_ + (fn * 16 + l15) * 128;                           \
            br[nh][fn][0] = *(const short8*)(rb_ + koff0);                           \
            br[nh][fn][1] = *(const short8*)(rb_ + koff1); } } while (0)
#define MMQ(mh, nh) do { __builtin_amdgcn_s_setprio(1);                              \
        _Pragma("unroll") for (int fm = 0; fm < 4; ++fm)                             \
        _Pragma("unroll") for (int fn = 0; fn < 2; ++fn) {                           \
            acc[(mh) * 4 + fm][(nh) * 2 + fn] = __builtin_amdgcn_mfma_f32_16x16x32_bf16( \
                ar[fm][0], br[nh][fn][0], acc[(mh) * 4 + fm][(nh) * 2 + fn], 0, 0, 0);   \
            acc[(mh) * 4 + fm][(nh) * 2 + fn] = __builtin_amdgcn_mfma_f32_16x16x32_bf16( \
                ar[fm][1], br[nh][fn][1], acc[(mh) * 4 + fm][(nh) * 2 + fn], 0, 0, 0); } \
        __builtin_amdgcn_s_setprio(0); } while (0)

    // prologue: tiles 0,1 fully staged (16 loads); drain tile 0 (oldest 8)
    SA(0, 0); SA(1, 0); SB(0, 0); SB(1, 0);
    SA(0, 1); SA(1, 1); SB(0, 1); SB(1, 1);
    asm volatile("s_waitcnt vmcnt(8)" ::: "memory");
    BAR();

    const int nk = K >> 6;
    for (int t = 0; t < nk; ++t) {
        const int p = t & 1;
        // P1: reads Ah0,Bh0 of buf p; stage Ah1(t+1) -> p^1 (freed (t-1).P3)
        LDA_SUB(0, p); LDB_SUB(0, p);
        if (t >= 1 && t + 1 < nk) SA(1, t + 1);
        BAR(); MMQ(0, 0); BAR();
        // P2: reads Bh1; stage Ah0(t+2) -> p (region freed at P1)
        LDB_SUB(1, p);
        if (t + 2 < nk) SA(0, t + 2);
        BAR(); MMQ(0, 1); BAR();
        // P3: reads Ah1; stage Bh0(t+2) -> p (freed at P1)
        LDA_SUB(1, p);
        if (t + 2 < nk) SB(0, t + 2);
        BAR(); MMQ(1, 0); BAR();
        // P4: regs only; stage Bh1(t+2) -> p (freed at P2); vmcnt(6) leaves the
        // 3 halves staged this tile, drains all of t+1
        if (t + 2 < nk) {
            SB(1, t + 2);
            asm volatile("s_waitcnt vmcnt(6)" ::: "memory");
        } else {
            asm volatile("s_waitcnt vmcnt(0)" ::: "memory");
        }
        BAR(); MMQ(1, 1); BAR();
    }
#undef SA
#undef SB
#undef LDA_SUB
#undef LDB_SUB
#undef MMQ

    if (EPI == 2) {
        // ---- fused key->gamma partial reduction (key stays in registers) ----
        float gqv[4], bqv[4], gkv[4], bkv[4];
#pragma unroll
        for (int nj = 0; nj < 4; ++nj) {
            const int n = nblk + (nj >> 1) * 128 + wc * 32 + (nj & 1) * 16 + l15;
            gqv[nj] = gq[n]; bqv[nj] = bq[n]; gkv[nj] = gk[n]; bkv[nj] = bk[n];
        }
        float* red = (float*)smem;           // [256 rows][4 wc][5] = 20 KB
#pragma unroll
        for (int mi = 0; mi < 8; ++mi) {
#pragma unroll
            for (int rr = 0; rr < 4; ++rr) {
                const int rloc = (mi >> 2) * 128 + wr * 64 + (mi & 3) * 16 + lhi * 4 + rr;
                const int m = mblk + rloc;
                const float mu = xs[m * 2], rx = xs[m * 2 + 1];
                float s1 = 0.f, s2 = 0.f, t1 = 0.f, t2 = 0.f, t3 = 0.f;
#pragma unroll
                for (int nj = 0; nj < 4; ++nj) {
                    const float kv = acc[mi][nj][rr];
                    const int n = nblk + (nj >> 1) * 128 + wc * 32 + (nj & 1) * 16 + l15;
                    const float xv = xq[(size_t)m * N + n];
                    const float q  = (xv - mu) * rx * gqv[nj] + bqv[nj];
                    const float qg = q * gkv[nj];
                    s1 += kv; s2 += kv * kv;
                    t1 += qg * kv; t2 += qg; t3 += q * bkv[nj];
                }
#pragma unroll
                for (int o = 1; o < 16; o <<= 1) {
                    s1 += __shfl_xor(s1, o); s2 += __shfl_xor(s2, o);
                    t1 += __shfl_xor(t1, o); t2 += __shfl_xor(t2, o);
                    t3 += __shfl_xor(t3, o);
                }
                if (l15 == 0) {
                    float* d = red + ((size_t)rloc * 4 + wc) * 5;
                    d[0] = s1; d[1] = s2; d[2] = t1; d[3] = t2; d[4] = t3;
                }
            }
        }
        BAR();
        const int nb = nblk >> 8;
        for (int e = tid; e < 1280; e += 512) {
            const int row = e / 5, v = e - row * 5;
            const float s = red[((size_t)row * 4 + 0) * 5 + v] + red[((size_t)row * 4 + 1) * 5 + v]
                          + red[((size_t)row * 4 + 2) * 5 + v] + red[((size_t)row * 4 + 3) * 5 + v];
            partial[((size_t)(mblk + row) * 8 + nb) * 5 + v] = s;
        }
    } else {
        // direct fragment epilogue: D row=(lane>>4)*4+r, col=lane&15
        float* Cf = (float*)Cout;
        if (EPI == 0 && GRID == 1) Cf += (size_t)blockIdx.y * M * N;   // K-split slab
#pragma unroll
        for (int mi = 0; mi < 8; ++mi) {
#pragma unroll
            for (int rr = 0; rr < 4; ++rr) {
                const int m = mblk + (mi >> 2) * 128 + wr * 64 + (mi & 3) * 16 + lhi * 4 + rr;
                const float sc = (EPI == 3) ? rowscale[m] : 1.0f;
#pragma unroll
                for (int nj = 0; nj < 4; ++nj) {
                    const int n = nblk + (nj >> 1) * 128 + wc * 32 + (nj & 1) * 16 + l15;
                    Cf[(size_t)m * N + n] = acc[mi][nj][rr] * sc;
                }
            }
        }
    }
}

extern "C" void kernel_launch(void* const* d_in, const int* in_sizes, int n_in,
                              void* d_out, int out_size, void* d_ws, size_t ws_size,
                              hipStream_t stream) {
    const float* x      = (const float*)d_in[0];
    const int*   hashes = (const int*)d_in[1];
    const int*   offs   = (const int*)d_in[2];
    const float* emb    = (const float*)d_in[3];
    const float* conv_w = (const float*)d_in[4];
    const float* lncg   = (const float*)d_in[5];
    const float* lncb   = (const float*)d_in[6];
    const float* Wk     = (const float*)d_in[7];
    const float* Wv     = (const float*)d_in[8];
    const float* Wo     = (const float*)d_in[9];
    const float* lnkg   = (const float*)d_in[10];
    const float* lnkb   = (const float*)d_in[11];
    const float* lnqg   = (const float*)d_in[12];
    const float* lnqb   = (const float*)d_in[13];

    // ws (~80 MB). key/value/E never materialized:
    // out = gamma * (e @ (Wo@Wv)^T), gather fused into conv.
    char* p = (char*)d_ws;
    float* W2part = (float*)p;  p += (size_t)KSP * HID * ED * 4;  // 16.8 MB
    u16*   A3     = (u16*)p;    p += (size_t)BT_ * K3 * 2;        // 25.2 MB
    u16*   Wk3    = (u16*)p;    p += (size_t)HID * K3 * 2;        // 3.1 MB
    u16*   WoP    = (u16*)p;    p += (size_t)HID * KW * 2;        // 25.2 MB
    u16*   WvP    = (u16*)p;    p += (size_t)ED * KW * 2;         // 3.1 MB
    u16*   W23    = (u16*)p;    p += (size_t)HID * K3 * 2;        // 3.1 MB
    float* xs     = (float*)p;  p += (size_t)BT_ * 2 * 4;         // 128 KB
    float* part   = (float*)p;  p += (size_t)BT_ * 8 * 5 * 4;     // 2.6 MB
    float* gamma  = (float*)p;  p += (size_t)BT_ * 4;             // 64 KB

    hipFuncSetAttribute((const void*)gemm8<0, 1>,
                        hipFuncAttributeMaxDynamicSharedMemorySize, 131072);
    hipFuncSetAttribute((const void*)gemm8<2, 0>,
                        hipFuncAttributeMaxDynamicSharedMemorySize, 131072);
    hipFuncSetAttribute((const void*)gemm8<3, 0>,
                        hipFuncAttributeMaxDynamicSharedMemorySize, 131072);

    k_cvt_wk3<<<(HID * ED) / 256, 256, 0, stream>>>(Wk, Wk3);
    k_packWo<<<(HID * HID) / 256, 256, 0, stream>>>(Wo, WoP);
    k_packWv<<<(HID * ED) / 256, 256, 0, stream>>>(Wv, WvP);
    k_conv<<<BT_, 256, 0, stream>>>(hashes, offs, emb, conv_w, lncg, lncb, A3);
    k_xstat<<<BT_, 256, 0, stream>>>(x, xs);

    // W2 = Wo @ Wv split-precision, K-split 8 x 768 -> f32 slabs
    gemm8<0, 1><<<dim3(HID / 256, KSP), 512, 131072, stream>>>(
        WoP, KW, WvP, KW, nullptr, W2part, HID, ED, KW / KSP,
        nullptr, nullptr, nullptr, nullptr, nullptr, nullptr, nullptr);
    k_w2pack<<<(HID * ED) / 256, 256, 0, stream>>>(W2part, W23);

    const dim3 grid((BT_ / 256) * (HID / 256));   // 512 = 64x8 tiles
    // key partials: A3 @ Wk3^T (K=768), gamma reduction fused in epilogue
    gemm8<2, 0><<<grid, 512, 131072, stream>>>(
        A3, K3, Wk3, K3, nullptr, nullptr, BT_, HID, K3,
        x, xs, lnqg, lnqb, lnkg, lnkb, part);
    k_gamma2<<<BT_ / 256, 256, 0, stream>>>(part, gamma);
    // out = gamma * (A3 @ W23^T)  (K=768) -> d_out f32
    gemm8<3, 0><<<grid, 512, 131072, stream>>>(
        A3, K3, W23, K3, gamma, d_out, BT_, HID, K3,
        nullptr, nullptr, nullptr, nullptr, nullptr, nullptr, nullptr);
}

// Round 17
// 253.435 us; speedup vs baseline: 1.5687x; 1.1427x over previous
//
#include <hip/hip_runtime.h>
#include <stdint.h>
#include <math.h>

#define B_   4
#define T_   4096
#define BT_  16384
#define HID  2048
#define ED   256
#define HD   32
#define NH   8
#define K3   768    // packed split K (hi|hi|lo)
#define KW   6144   // packed split K for W2 = Wo@Wv (hi|hi|lo over 2048)
#define KSP  8      // K-split for W2 GEMM

typedef unsigned short u16;
typedef __attribute__((ext_vector_type(8))) short short8;
typedef __attribute__((ext_vector_type(4))) float f32x4;

typedef __attribute__((address_space(1))) void gvoid;
typedef __attribute__((address_space(3))) void lvoid;

__device__ __forceinline__ float bf2f(u16 h) {
    return __uint_as_float(((uint32_t)h) << 16);
}
__device__ __forceinline__ u16 f2bf(float f) {
    uint32_t u = __float_as_uint(f);
    u += 0x7FFFu + ((u >> 16) & 1u);   // round-to-nearest-even
    return (u16)(u >> 16);
}
__device__ __forceinline__ void gld_lds16(const void* g, void* l) {
    __builtin_amdgcn_global_load_lds((gvoid*)(uintptr_t)g, (lvoid*)(uintptr_t)l, 16, 0, 0);
}
__device__ __forceinline__ void BAR() {
    asm volatile("" ::: "memory");
    __builtin_amdgcn_s_barrier();
    asm volatile("" ::: "memory");
}

// ---- fused packs: Wk -> Wk3 [hi|lo|hi](768); Wo -> WoP [hi|hi|lo](6144);
//      Wv -> WvP [hi|lo|hi](6144, transposed) ----
__global__ void k_packs(const float* __restrict__ Wk, const float* __restrict__ Wo,
                        const float* __restrict__ Wv, u16* __restrict__ wk3,
                        u16* __restrict__ wop, u16* __restrict__ wvp) {
    int i = blockIdx.x * 256 + threadIdx.x;
    if (i < HID * ED) {
        int n = i >> 8, c = i & 255;
        float f = Wk[i];
        u16 h = f2bf(f);
        wk3[(size_t)n * K3 + c]       = h;
        wk3[(size_t)n * K3 + 256 + c] = f2bf(f - bf2f(h));
        wk3[(size_t)n * K3 + 512 + c] = h;
        // Wv (same index space): row n (HID), col c (ED) -> WvP transposed
        float g = Wv[i];
        u16 hg = f2bf(g);
        wvp[(size_t)c * KW + n]        = hg;
        wvp[(size_t)c * KW + 2048 + n] = f2bf(g - bf2f(hg));
        wvp[(size_t)c * KW + 4096 + n] = hg;
    } else {
        int j = i - HID * ED;             // over HID*HID
        int o = j >> 11, n = j & 2047;
        float f = Wo[j];
        u16 h = f2bf(f);
        wop[(size_t)o * KW + n]        = h;
        wop[(size_t)o * KW + 2048 + n] = h;
        wop[(size_t)o * KW + 4096 + n] = f2bf(f - bf2f(h));
    }
}

// ---- reduce 8 K-split partials -> W2 f32 -> W23 [2048][768] = [hi | lo | hi] ----
__global__ void k_w2pack(const float* __restrict__ part, u16* __restrict__ w23) {
    int i = blockIdx.x * 256 + threadIdx.x;   // over 2048*256
    int o = i >> 8, c = i & 255;
    float s = 0.f;
#pragma unroll
    for (int k = 0; k < KSP; ++k) s += part[(size_t)k * HID * ED + i];
    u16 h = f2bf(s);
    w23[(size_t)o * K3 + c]       = h;
    w23[(size_t)o * K3 + 256 + c] = f2bf(s - bf2f(h));
    w23[(size_t)o * K3 + 512 + c] = h;
}

// ---- fused front end: blocks [0,BT_) = gather+conv+LN+silu+residual -> A3;
//      blocks [BT_, 2*BT_) = x row stats ----
__global__ void k_front(const int* __restrict__ hashes, const int* __restrict__ offs,
                        const float* __restrict__ tab, const float* __restrict__ w,
                        const float* __restrict__ lng, const float* __restrict__ lnb,
                        u16* __restrict__ a3,
                        const float* __restrict__ x, float* __restrict__ xs) {
    __shared__ float red[8];
    const int tid = threadIdx.x;          // 256
    const int wid = tid >> 6, lane = tid & 63;
    if (blockIdx.x < BT_) {
        const int bt = blockIdx.x;
        const int b = bt >> 12;           // T_ = 4096
        const int t = bt & 4095;
        const int ch = tid;
        const int head = ch >> 5, d = ch & 31;
        const int off = offs[head];
        float c = 0.f, self = 0.f;
#pragma unroll
        for (int k = 0; k < 4; ++k) {
            const int tt = t - 9 + 3 * k; // taps at t-9, t-6, t-3, t
            if (tt >= 0) {
                const int row = hashes[(b * T_ + tt) * NH + head] + off;
                const float ev = tab[(size_t)row * HD + d];
                c += w[ch * 4 + k] * ev;
                if (k == 3) self = ev;
            }
        }
        float s = c, s2 = c * c;
#pragma unroll
        for (int o = 32; o; o >>= 1) { s += __shfl_xor(s, o); s2 += __shfl_xor(s2, o); }
        if (!lane) { red[wid] = s; red[4 + wid] = s2; }
        __syncthreads();
        s  = red[0] + red[1] + red[2] + red[3];
        s2 = red[4] + red[5] + red[6] + red[7];
        const float mean = s * (1.f / 256.f);
        const float var  = s2 * (1.f / 256.f) - mean * mean;
        float ln = (c - mean) * rsqrtf(var + 1e-5f) * lng[ch] + lnb[ch];
        float si = ln / (1.f + expf(-ln));    // silu
        float ev = self + si;
        u16 h = f2bf(ev);
        a3[(size_t)bt * K3 + ch]       = h;
        a3[(size_t)bt * K3 + 256 + ch] = h;
        a3[(size_t)bt * K3 + 512 + ch] = f2bf(ev - bf2f(h));
    } else {
        const int m = blockIdx.x - BT_;
        const f32x4* xr = (const f32x4*)(x + (size_t)m * HID);
        float sx = 0.f, sx2 = 0.f;
#pragma unroll
        for (int i = 0; i < 2; ++i) {
            f32x4 xv = xr[tid + i * 256];
#pragma unroll
            for (int c = 0; c < 4; ++c) { sx += xv[c]; sx2 += xv[c] * xv[c]; }
        }
#pragma unroll
        for (int o = 32; o; o >>= 1) { sx += __shfl_xor(sx, o); sx2 += __shfl_xor(sx2, o); }
        if (!lane) { red[wid] = sx; red[4 + wid] = sx2; }
        __syncthreads();
        if (tid == 0) {
            sx  = red[0] + red[1] + red[2] + red[3];
            sx2 = red[4] + red[5] + red[6] + red[7];
            const float inv = 1.f / (float)HID;
            const float mu = sx * inv, var = sx2 * inv - mu * mu;
            xs[m * 2]     = mu;
            xs[m * 2 + 1] = rsqrtf(var + 1e-5f);
        }
    }
}

// ---------------- finalize gamma from 8 partial slices ----------------
// dot = rk*(T1 - mu_k*T2) + T3 ; partial[m][nb][5] = {S1,S2,T1,T2,T3}
__global__ void k_gamma2(const float* __restrict__ partial, float* __restrict__ gamma) {
    const int m = blockIdx.x * 256 + threadIdx.x;
    float s[5] = {0.f, 0.f, 0.f, 0.f, 0.f};
    const float* p = partial + (size_t)m * 40;
#pragma unroll
    for (int nb = 0; nb < 8; ++nb)
#pragma unroll
        for (int v = 0; v < 5; ++v) s[v] += p[nb * 5 + v];
    const float inv = 1.f / (float)HID;
    const float mu = s[0] * inv, var = s[1] * inv - mu * mu;
    const float rk = rsqrtf(var + 1e-5f);
    const float dot = rk * (s[2] - mu * s[3]) + s[4];
    const float gd = dot * 0.022097086912079608f;   // 1/sqrt(2048)
    const float sg = (gd > 0.f) ? 1.f : ((gd < 0.f) ? -1.f : 0.f);
    const float sv = sqrtf(fmaxf(fabsf(gd), 1e-6f)) * sg;
    gamma[m] = 1.f / (1.f + expf(-sv));
}

// ================= 256x256 / BK=64 bf16 MFMA GEMM — pipelined, chunk-aligned =================
// (r10/r11-validated core: chunk-pure reads, 4-phase staging, vmcnt(6).)
// A row = mh*128 + wr*64 + fm*16 + l15 (P1 reads exactly A h0, P3 exactly h1)
// B row = nh*128 + wc*32 + fn*16 + l15 (P1 reads exactly B h0, P2 exactly h1)
// Schedule (tile t, buf p=t&1): P1 reads Ah0,Bh0 + stage Ah1(t+1)->p^1; P2 reads
// Bh1 + stage Ah0(t+2)->p; P3 reads Ah1 + stage Bh0(t+2)->p; P4 regs-only +
// stage Bh1(t+2)->p + vmcnt(6) (drains ALL of t+1, issued 4-8 phases earlier).
// Schedule verified by induction for nk = 4 / 12 / 24.
// GRID=0: 2D XCD chunking (grid 64x8 tiles). GRID=1: row-major + K-split via
// blockIdx.y. EPI: 0 = f32 K-split slab; 2 = fused key->gamma partials
// (key never materialized); 3 = f32 store with rowscale.
template <int EPI, int GRID>
__global__ __launch_bounds__(512, 2)
void gemm8(const u16* __restrict__ A, int lda, const u16* __restrict__ Bm, int ldb,
           const float* __restrict__ rowscale, void* __restrict__ Cout,
           int M, int N, int K,
           const float* __restrict__ xq, const float* __restrict__ xs,
           const float* __restrict__ gq, const float* __restrict__ bq,
           const float* __restrict__ gk, const float* __restrict__ bk,
           float* __restrict__ partial) {
    extern __shared__ char smem[];
    const int tid = threadIdx.x, wid = tid >> 6, lane = tid & 63;
    const int l15 = lane & 15, lhi = lane >> 4;
    const int wr = wid >> 2, wc = wid & 3;

    const int id = blockIdx.x;
    int mblk, nblk;
    if (GRID == 0) {
        // 2D XCD chunking: xcd = id&7 owns an 8(m) x 8(n) tile chunk
        const int xcd = id & 7, loc = id >> 3;
        mblk = ((xcd << 3) + (loc & 7)) << 8;
        nblk = (loc >> 3) << 8;
    } else {
        const int tiles_m = M >> 8;
        mblk = (id % tiles_m) << 8;
        nblk = (id / tiles_m) << 8;
        const size_t koff = (size_t)blockIdx.y * K;
        A  += koff;
        Bm += koff;
    }

    f32x4 acc[8][4];
#pragma unroll
    for (int i = 0; i < 8; ++i)
#pragma unroll
        for (int j = 0; j < 4; ++j) acc[i][j] = f32x4{0.f, 0.f, 0.f, 0.f};

    const int srow = tid >> 3;
    const int scol = ((tid & 7) << 3) ^ ((srow & 7) << 3);
    const u16* aS[4];
    const u16* bS[4];
#pragma unroll
    for (int h = 0; h < 2; ++h)
#pragma unroll
        for (int r = 0; r < 2; ++r) {
            aS[h * 2 + r] = A  + (size_t)(mblk + h * 128 + r * 64 + srow) * lda + scol;
            bS[h * 2 + r] = Bm + (size_t)(nblk + h * 128 + r * 64 + srow) * ldb + scol;
        }
    const int wb = wid * 1024;

    const int koff0 = (lhi * 16) ^ ((l15 & 7) << 4);
    const int koff1 = (64 + lhi * 16) ^ ((l15 & 7) << 4);

    short8 ar[4][2], br[2][2][2];

#define SA(h, tt) do { const int kk_ = (tt) << 6;                                    \
        char* d_ = smem + (((tt) & 1) * 32768) + (h) * 16384 + wb;                   \
        gld_lds16(aS[(h) * 2 + 0] + kk_, d_);                                        \
        gld_lds16(aS[(h) * 2 + 1] + kk_, d_ + 8192); } while (0)
#define SB(h, tt) do { const int kk_ = (tt) << 6;                                    \
        char* d_ = smem + 65536 + (((tt) & 1) * 32768) + (h) * 16384 + wb;           \
        gld_lds16(bS[(h) * 2 + 0] + kk_, d_);                                        \
        gld_lds16(bS[(h) * 2 + 1] + kk_, d_ + 8192); } while (0)
#define LDA_SUB(mh, p) do {                                                          \
        const char* ab_ = smem + (p) * 32768 + ((mh) * 128 + wr * 64) * 128;         \
        _Pragma("unroll") for (int fm = 0; fm < 4; ++fm) {                           \
            const char* rb_ = ab_ + (fm * 16 + l15) * 128;                           \
            ar[fm][0] = *(const short8*)(rb_ + koff0);                               \
            ar[fm][1] = *(const short8*)(rb_ + koff1); } } while (0)
#define LDB_SUB(nh, p) do {                                                          \
        const char* bb_ = smem + 65536 + (p) * 32768 + ((nh) * 128 + wc * 32) * 128; \
        _Pragma("unroll") for (int fn = 0; fn < 2; ++fn) {                           \
            const char* rb_ = bb_ + (fn * 16 + l15) * 128;                           \
            br[nh][fn][0] = *(const short8*)(rb_ + koff0);                           \
            br[nh][fn][1] = *(const short8*)(rb_ + koff1); } } while (0)
#define MMQ(mh, nh) do { __builtin_amdgcn_s_setprio(1);                              \
        _Pragma("unroll") for (int fm = 0; fm < 4; ++fm)                             \
        _Pragma("unroll") for (int fn = 0; fn < 2; ++fn) {                           \
            acc[(mh) * 4 + fm][(nh) * 2 + fn] = __builtin_amdgcn_mfma_f32_16x16x32_bf16( \
                ar[fm][0], br[nh][fn][0], acc[(mh) * 4 + fm][(nh) * 2 + fn], 0, 0, 0);   \
            acc[(mh) * 4 + fm][(nh) * 2 + fn] = __builtin_amdgcn_mfma_f32_16x16x32_bf16( \
                ar[fm][1], br[nh][fn][1], acc[(mh) * 4 + fm][(nh) * 2 + fn], 0, 0, 0); } \
        __builtin_amdgcn_s_setprio(0); } while (0)

    // prologue: tiles 0,1 fully staged (16 loads); drain tile 0 (oldest 8)
    SA(0, 0); SA(1, 0); SB(0, 0); SB(1, 0);
    SA(0, 1); SA(1, 1); SB(0, 1); SB(1, 1);
    asm volatile("s_waitcnt vmcnt(8)" ::: "memory");
    BAR();

    const int nk = K >> 6;
    for (int t = 0; t < nk; ++t) {
        const int p = t & 1;
        // P1: reads Ah0,Bh0 of buf p; stage Ah1(t+1) -> p^1 (freed (t-1).P3)
        LDA_SUB(0, p); LDB_SUB(0, p);
        if (t >= 1 && t + 1 < nk) SA(1, t + 1);
        BAR(); MMQ(0, 0); BAR();
        // P2: reads Bh1; stage Ah0(t+2) -> p (region freed at P1)
        LDB_SUB(1, p);
        if (t + 2 < nk) SA(0, t + 2);
        BAR(); MMQ(0, 1); BAR();
        // P3: reads Ah1; stage Bh0(t+2) -> p (freed at P1)
        LDA_SUB(1, p);
        if (t + 2 < nk) SB(0, t + 2);
        BAR(); MMQ(1, 0); BAR();
        // P4: regs only; stage Bh1(t+2) -> p (freed at P2); vmcnt(6) leaves the
        // 3 halves staged this tile, drains all of t+1
        if (t + 2 < nk) {
            SB(1, t + 2);
            asm volatile("s_waitcnt vmcnt(6)" ::: "memory");
        } else {
            asm volatile("s_waitcnt vmcnt(0)" ::: "memory");
        }
        BAR(); MMQ(1, 1); BAR();
    }
#undef SA
#undef SB
#undef LDA_SUB
#undef LDB_SUB
#undef MMQ

    if (EPI == 2) {
        // ---- fused key->gamma partial reduction (key stays in registers) ----
        float gqv[4], bqv[4], gkv[4], bkv[4];
#pragma unroll
        for (int nj = 0; nj < 4; ++nj) {
            const int n = nblk + (nj >> 1) * 128 + wc * 32 + (nj & 1) * 16 + l15;
            gqv[nj] = gq[n]; bqv[nj] = bq[n]; gkv[nj] = gk[n]; bkv[nj] = bk[n];
        }
        float* red = (float*)smem;           // [256 rows][4 wc][5] = 20 KB
#pragma unroll
        for (int mi = 0; mi < 8; ++mi) {
#pragma unroll
            for (int rr = 0; rr < 4; ++rr) {
                const int rloc = (mi >> 2) * 128 + wr * 64 + (mi & 3) * 16 + lhi * 4 + rr;
                const int m = mblk + rloc;
                const float mu = xs[m * 2], rx = xs[m * 2 + 1];
                float s1 = 0.f, s2 = 0.f, t1 = 0.f, t2 = 0.f, t3 = 0.f;
#pragma unroll
                for (int nj = 0; nj < 4; ++nj) {
                    const float kv = acc[mi][nj][rr];
                    const int n = nblk + (nj >> 1) * 128 + wc * 32 + (nj & 1) * 16 + l15;
                    const float xv = xq[(size_t)m * N + n];
                    const float q  = (xv - mu) * rx * gqv[nj] + bqv[nj];
                    const float qg = q * gkv[nj];
                    s1 += kv; s2 += kv * kv;
                    t1 += qg * kv; t2 += qg; t3 += q * bkv[nj];
                }
#pragma unroll
                for (int o = 1; o < 16; o <<= 1) {
                    s1 += __shfl_xor(s1, o); s2 += __shfl_xor(s2, o);
                    t1 += __shfl_xor(t1, o); t2 += __shfl_xor(t2, o);
                    t3 += __shfl_xor(t3, o);
                }
                if (l15 == 0) {
                    float* d = red + ((size_t)rloc * 4 + wc) * 5;
                    d[0] = s1; d[1] = s2; d[2] = t1; d[3] = t2; d[4] = t3;
                }
            }
        }
        BAR();
        const int nb = nblk >> 8;
        for (int e = tid; e < 1280; e += 512) {
            const int row = e / 5, v = e - row * 5;
            const float s = red[((size_t)row * 4 + 0) * 5 + v] + red[((size_t)row * 4 + 1) * 5 + v]
                          + red[((size_t)row * 4 + 2) * 5 + v] + red[((size_t)row * 4 + 3) * 5 + v];
            partial[((size_t)(mblk + row) * 8 + nb) * 5 + v] = s;
        }
    } else {
        // direct fragment epilogue: D row=(lane>>4)*4+r, col=lane&15
        float* Cf = (float*)Cout;
        if (EPI == 0 && GRID == 1) Cf += (size_t)blockIdx.y * M * N;   // K-split slab
#pragma unroll
        for (int mi = 0; mi < 8; ++mi) {
#pragma unroll
            for (int rr = 0; rr < 4; ++rr) {
                const int m = mblk + (mi >> 2) * 128 + wr * 64 + (mi & 3) * 16 + lhi * 4 + rr;
                const float sc = (EPI == 3) ? rowscale[m] : 1.0f;
#pragma unroll
                for (int nj = 0; nj < 4; ++nj) {
                    const int n = nblk + (nj >> 1) * 128 + wc * 32 + (nj & 1) * 16 + l15;
                    Cf[(size_t)m * N + n] = acc[mi][nj][rr] * sc;
                }
            }
        }
    }
}

extern "C" void kernel_launch(void* const* d_in, const int* in_sizes, int n_in,
                              void* d_out, int out_size, void* d_ws, size_t ws_size,
                              hipStream_t stream) {
    const float* x      = (const float*)d_in[0];
    const int*   hashes = (const int*)d_in[1];
    const int*   offs   = (const int*)d_in[2];
    const float* emb    = (const float*)d_in[3];
    const float* conv_w = (const float*)d_in[4];
    const float* lncg   = (const float*)d_in[5];
    const float* lncb   = (const float*)d_in[6];
    const float* Wk     = (const float*)d_in[7];
    const float* Wv     = (const float*)d_in[8];
    const float* Wo     = (const float*)d_in[9];
    const float* lnkg   = (const float*)d_in[10];
    const float* lnkb   = (const float*)d_in[11];
    const float* lnqg   = (const float*)d_in[12];
    const float* lnqb   = (const float*)d_in[13];

    // ws (~80 MB). key/value/E never materialized:
    // out = gamma * (e @ (Wo@Wv)^T), gather fused into conv (k_front).
    char* p = (char*)d_ws;
    float* W2part = (float*)p;  p += (size_t)KSP * HID * ED * 4;  // 16.8 MB
    u16*   A3     = (u16*)p;    p += (size_t)BT_ * K3 * 2;        // 25.2 MB
    u16*   Wk3    = (u16*)p;    p += (size_t)HID * K3 * 2;        // 3.1 MB
    u16*   WoP    = (u16*)p;    p += (size_t)HID * KW * 2;        // 25.2 MB
    u16*   WvP    = (u16*)p;    p += (size_t)ED * KW * 2;         // 3.1 MB
    u16*   W23    = (u16*)p;    p += (size_t)HID * K3 * 2;        // 3.1 MB
    float* xs     = (float*)p;  p += (size_t)BT_ * 2 * 4;         // 128 KB
    float* part   = (float*)p;  p += (size_t)BT_ * 8 * 5 * 4;     // 2.6 MB
    float* gamma  = (float*)p;  p += (size_t)BT_ * 4;             // 64 KB

    hipFuncSetAttribute((const void*)gemm8<0, 1>,
                        hipFuncAttributeMaxDynamicSharedMemorySize, 131072);
    hipFuncSetAttribute((const void*)gemm8<2, 0>,
                        hipFuncAttributeMaxDynamicSharedMemorySize, 131072);
    hipFuncSetAttribute((const void*)gemm8<3, 0>,
                        hipFuncAttributeMaxDynamicSharedMemorySize, 131072);

    // fused packs: Wk3 + WvP (first HID*ED items) and WoP (next HID*HID)
    k_packs<<<(HID * ED + HID * HID) / 256, 256, 0, stream>>>(Wk, Wo, Wv, Wk3, WoP, WvP);
    // fused front end: conv->A3 (blocks 0..BT_) and x stats (blocks BT_..2*BT_)
    k_front<<<2 * BT_, 256, 0, stream>>>(hashes, offs, emb, conv_w, lncg, lncb, A3, x, xs);

    // W2 = Wo @ Wv split-precision, K-split 8 x 768 -> f32 slabs
    gemm8<0, 1><<<dim3(HID / 256, KSP), 512, 131072, stream>>>(
        WoP, KW, WvP, KW, nullptr, W2part, HID, ED, KW / KSP,
        nullptr, nullptr, nullptr, nullptr, nullptr, nullptr, nullptr);
    k_w2pack<<<(HID * ED) / 256, 256, 0, stream>>>(W2part, W23);

    const dim3 grid((BT_ / 256) * (HID / 256));   // 512 = 64x8 tiles
    // key partials: A3 @ Wk3^T (K=768 split), gamma reduction fused in epilogue
    gemm8<2, 0><<<grid, 512, 131072, stream>>>(
        A3, K3, Wk3, K3, nullptr, nullptr, BT_, HID, K3,
        x, xs, lnqg, lnqb, lnkg, lnkb, part);
    k_gamma2<<<BT_ / 256, 256, 0, stream>>>(part, gamma);
    // out = gamma * (e_hi @ W2_hi^T)  (K=256 plain bf16 — error budget allows;
    // A3/W23 first 256 cols, strides 768) -> d_out f32
    gemm8<3, 0><<<grid, 512, 131072, stream>>>(
        A3, K3, W23, K3, gamma, d_out, BT_, HID, ED,
        nullptr, nullptr, nullptr, nullptr, nullptr, nullptr, nullptr);
}